// Round 1
// baseline (15832.765 us; speedup 1.0000x reference)
//
#include <hip/hip_runtime.h>

// ---------------------------------------------------------------------------
// Seq2Seq LSTM (2-layer encoder S=256, 2-layer decoder HORIZON=24, feedback)
// B=1024, H=512, IN=64, NT=8.  f16 MFMA (16x16x32), fp32 cell state.
//
// Per-step fused GEMM+cell kernel:
//   gates(M=1024 x N=2048) = [A0 | A1] @ Wp^T + bp   (K = K0+K1, mult of 32)
//   Wp rows gate-interleaved: packed row r = 4*j + g  (g in {i,f,g,o})
//   -> MFMA C-layout 4-lane groups hold one cell's quadruple; shfl-gather,
//      sigmoid/tanh epilogue in-register, h out f16, c in/out fp32.
// ---------------------------------------------------------------------------

typedef _Float16 half_t;
typedef _Float16 half8 __attribute__((ext_vector_type(8)));
typedef float floatx4 __attribute__((ext_vector_type(4)));

#define B_ 1024
#define S_ 256
#define IN_ 64
#define H_ 512
#define NT_ 8
#define HOR_ 24
#define NG_ 2048  // 4*H

__device__ __forceinline__ float sig_(float x) { return 1.0f / (1.0f + __expf(-x)); }

__device__ __forceinline__ void async_cp16(const void* g, void* l) {
  // global -> LDS direct, 16B per lane; LDS dest = wave-uniform base + lane*16
  __builtin_amdgcn_global_load_lds((const __attribute__((address_space(1))) void*)g,
                                   (__attribute__((address_space(3))) void*)l,
                                   16, 0, 0);
}

// ---------------- setup kernels ----------------

__global__ void k_convert_x(const float* __restrict__ x, half_t* __restrict__ xf, int n) {
  int i = blockIdx.x * 256 + threadIdx.x;
  if (i < n) xf[i] = (half_t)x[i];
}

// Pack [Wih | Whh] -> Wp (2048 x K) f16, row r = 4*j+g  <- src row g*512+j.
// K0real real input cols, zero-padded to K0pad, then 512 Whh cols.
__global__ void k_pack(const float* __restrict__ Wih, const float* __restrict__ Whh,
                       const float* __restrict__ bias,
                       half_t* __restrict__ Wp, float* __restrict__ bp,
                       int K0real, int K0pad, int K) {
  int i = blockIdx.x * 256 + threadIdx.x;
  if (i >= NG_ * K) return;
  int r = i / K;
  int k = i - r * K;
  int j = r >> 2, g = r & 3;
  int src = g * H_ + j;
  float v;
  if (k < K0pad) v = (k < K0real) ? Wih[src * K0real + k] : 0.0f;
  else           v = Whh[src * H_ + (k - K0pad)];
  Wp[i] = (half_t)v;
  if (k == 0) bp[r] = bias[src];
}

__global__ void k_zero_state(float* c0, float* c1, half_t* h0a, half_t* h0b,
                             half_t* h1a, half_t* h1b, half_t* dpad) {
  int i = blockIdx.x * 256 + threadIdx.x;  // 0 .. B*H-1 (524288)
  c0[i] = 0.0f; c1[i] = 0.0f;
  h0a[i] = (half_t)0.0f; h0b[i] = (half_t)0.0f;
  h1a[i] = (half_t)0.0f; h1b[i] = (half_t)0.0f;
  if (i < B_ * 32) dpad[i] = (half_t)0.0f;
}

// ---------------- fused LSTM cell kernel ----------------
// grid: (2048/128, 1024/64) ; block 256 (4 waves); WG tile 64(M) x 128(N gates)
// wave tile 32x64 = 2x4 MFMA 16x16 tiles.

__global__ __launch_bounds__(256, 1)
void k_cell(const half_t* __restrict__ A0, int ldA0, int K0,
            const half_t* __restrict__ A1, int ldA1,
            const half_t* __restrict__ Wp, const float* __restrict__ bp, int K,
            float* __restrict__ cio, half_t* __restrict__ hout) {
  __shared__ __align__(16) half_t ldsA[64 * 32];   // 4 subtiles of 16x32
  __shared__ __align__(16) half_t ldsB[128 * 32];  // 8 subtiles of 16x32

  const int tid = threadIdx.x;
  const int l   = tid & 63;
  const int w   = tid >> 6;    // wave 0..3
  const int wm  = w >> 1;      // M-half (32 rows)
  const int wn  = w & 1;       // N-half (64 cols)
  const int M0  = blockIdx.y * 64;
  const int N0  = blockIdx.x * 128;

  // --- staging addressing: lane -> (row l>>2, 16B chunk (l&3)^((l>>2)&3)) ---
  const int srow = l >> 2;
  const int koff = (((l & 3) ^ (srow & 3)) * 8);  // halves

  const int am = M0 + 16 * w + srow;                         // A subtile w
  const half_t* a0p = A0 + (size_t)am * ldA0 + koff;
  const half_t* a1p = A1 + (size_t)am * ldA1 + koff;
  half_t* ldsA_dst = &ldsA[w * 512];

  const int bn = N0 + 32 * w + srow;                         // B subtiles 2w,2w+1
  const half_t* b0p = Wp + (size_t)bn * K + koff;
  const half_t* b1p = Wp + (size_t)(bn + 16) * K + koff;
  half_t* ldsB_dst0 = &ldsB[(2 * w) * 512];
  half_t* ldsB_dst1 = &ldsB[(2 * w + 1) * 512];

  // --- fragment read addressing (A-operand layout: row=lane&15, k=quad*8+j) ---
  const int fr = l & 15;
  const int fq = l >> 4;
  const int fo = fr * 32 + ((fq ^ (fr & 3)) * 8);  // swizzle-matched
  const half_t* fa0 = &ldsA[(2 * wm + 0) * 512 + fo];
  const half_t* fa1 = &ldsA[(2 * wm + 1) * 512 + fo];
  const half_t* fb0 = &ldsB[(4 * wn + 0) * 512 + fo];
  const half_t* fb1 = &ldsB[(4 * wn + 1) * 512 + fo];
  const half_t* fb2 = &ldsB[(4 * wn + 2) * 512 + fo];
  const half_t* fb3 = &ldsB[(4 * wn + 3) * 512 + fo];

  floatx4 zero = {0.f, 0.f, 0.f, 0.f};
  floatx4 acc[2][4];
#pragma unroll
  for (int mt = 0; mt < 2; ++mt)
#pragma unroll
    for (int nt = 0; nt < 4; ++nt) acc[mt][nt] = zero;

  const int KC  = K >> 5;
  const int K0C = K0 >> 5;
  for (int kc = 0; kc < KC; ++kc) {
    const int kb = kc * 32;
    const half_t* as = (kc < K0C) ? (a0p + kb) : (a1p + (kb - K0));
    async_cp16(as, ldsA_dst);
    async_cp16(b0p + kb, ldsB_dst0);
    async_cp16(b1p + kb, ldsB_dst1);
    __syncthreads();  // drains vmcnt(0) -> staged data visible

    half8 av0 = *(const half8*)fa0;
    half8 av1 = *(const half8*)fa1;
    half8 bv0 = *(const half8*)fb0;
    half8 bv1 = *(const half8*)fb1;
    half8 bv2 = *(const half8*)fb2;
    half8 bv3 = *(const half8*)fb3;

    acc[0][0] = __builtin_amdgcn_mfma_f32_16x16x32_f16(av0, bv0, acc[0][0], 0, 0, 0);
    acc[0][1] = __builtin_amdgcn_mfma_f32_16x16x32_f16(av0, bv1, acc[0][1], 0, 0, 0);
    acc[0][2] = __builtin_amdgcn_mfma_f32_16x16x32_f16(av0, bv2, acc[0][2], 0, 0, 0);
    acc[0][3] = __builtin_amdgcn_mfma_f32_16x16x32_f16(av0, bv3, acc[0][3], 0, 0, 0);
    acc[1][0] = __builtin_amdgcn_mfma_f32_16x16x32_f16(av1, bv0, acc[1][0], 0, 0, 0);
    acc[1][1] = __builtin_amdgcn_mfma_f32_16x16x32_f16(av1, bv1, acc[1][1], 0, 0, 0);
    acc[1][2] = __builtin_amdgcn_mfma_f32_16x16x32_f16(av1, bv2, acc[1][2], 0, 0, 0);
    acc[1][3] = __builtin_amdgcn_mfma_f32_16x16x32_f16(av1, bv3, acc[1][3], 0, 0, 0);
    __syncthreads();  // protect LDS reuse
  }

  // --- epilogue: bias + gather (i,f,g,o) within 4-lane groups + cell update ---
  const int base = l & ~3;
  const int gsel = l & 3;
#pragma unroll
  for (int nt = 0; nt < 4; ++nt) {
    const int ncol = N0 + wn * 64 + nt * 16 + fr;    // packed gate column
    const float bc = bp[ncol];
    const int jg = ((N0 + wn * 64 + nt * 16) >> 2) + (fr >> 2);  // cell index
#pragma unroll
    for (int mt = 0; mt < 2; ++mt) {
#pragma unroll
      for (int r = 0; r < 4; ++r) {
        float v  = acc[mt][nt][r] + bc;
        float gi = __shfl(v, base + 0);
        float gf = __shfl(v, base + 1);
        float gg = __shfl(v, base + 2);
        float go = __shfl(v, base + 3);
        const int mg = M0 + wm * 32 + mt * 16 + fq * 4 + r;
        const size_t cidx = (size_t)mg * H_ + jg;
        const float cold = cio[cidx];
        const float cn = sig_(gf) * cold + sig_(gi) * tanhf(gg);
        const float hn = sig_(go) * tanhf(cn);
        if (gsel == 0) hout[cidx] = (half_t)hn;
        else if (gsel == 1) cio[cidx] = cn;
      }
    }
  }
}

// ---------------- decoder output projection + feedback ----------------
__global__ void k_fc(const half_t* __restrict__ h1, const float* __restrict__ Wfc,
                     const float* __restrict__ bfc, float* __restrict__ out,
                     half_t* __restrict__ dpad, int t) {
  int i = blockIdx.x * 256 + threadIdx.x;
  if (i >= B_ * NT_) return;
  int b = i >> 3, n = i & 7;
  const half_t* hr = h1 + (size_t)b * H_;
  const float*  wr = Wfc + (size_t)n * H_;
  float s = bfc[n];
#pragma unroll 8
  for (int k = 0; k < H_; ++k) s += (float)hr[k] * wr[k];
  out[((size_t)b * HOR_ + t) * NT_ + n] = s;
  dpad[b * 32 + n] = (half_t)s;  // feedback (cols 8..31 stay zero)
}

// ---------------- host ----------------

extern "C" void kernel_launch(void* const* d_in, const int* in_sizes, int n_in,
                              void* d_out, int out_size, void* d_ws, size_t ws_size,
                              hipStream_t stream) {
  (void)in_sizes; (void)n_in; (void)out_size; (void)ws_size;
  const float* x     = (const float*)d_in[0];
  const float* Wih0e = (const float*)d_in[1];
  const float* Whh0e = (const float*)d_in[2];
  const float* b0e   = (const float*)d_in[3];
  const float* Wih1e = (const float*)d_in[4];
  const float* Whh1e = (const float*)d_in[5];
  const float* b1e   = (const float*)d_in[6];
  const float* Wih0d = (const float*)d_in[7];
  const float* Whh0d = (const float*)d_in[8];
  const float* b0d   = (const float*)d_in[9];
  const float* Wih1d = (const float*)d_in[10];
  const float* Whh1d = (const float*)d_in[11];
  const float* b1d   = (const float*)d_in[12];
  const float* Wfc   = (const float*)d_in[13];
  const float* bfc   = (const float*)d_in[14];
  float* out = (float*)d_out;

  char* p = (char*)d_ws;
  auto alloc = [&](size_t bytes) {
    char* r = p;
    p += (bytes + 255) & ~(size_t)255;
    return r;
  };
  half_t* xf    = (half_t*)alloc((size_t)B_ * S_ * IN_ * 2);   // 33.5 MB
  half_t* Wp0e  = (half_t*)alloc((size_t)NG_ * 576 * 2);
  half_t* Wp1e  = (half_t*)alloc((size_t)NG_ * 1024 * 2);
  half_t* Wp0d  = (half_t*)alloc((size_t)NG_ * 544 * 2);
  half_t* Wp1d  = (half_t*)alloc((size_t)NG_ * 1024 * 2);
  float*  bp0e  = (float*)alloc(NG_ * 4);
  float*  bp1e  = (float*)alloc(NG_ * 4);
  float*  bp0d  = (float*)alloc(NG_ * 4);
  float*  bp1d  = (float*)alloc(NG_ * 4);
  half_t* h0buf[2] = {(half_t*)alloc((size_t)B_ * H_ * 2), (half_t*)alloc((size_t)B_ * H_ * 2)};
  half_t* h1buf[2] = {(half_t*)alloc((size_t)B_ * H_ * 2), (half_t*)alloc((size_t)B_ * H_ * 2)};
  float*  c0    = (float*)alloc((size_t)B_ * H_ * 4);
  float*  c1    = (float*)alloc((size_t)B_ * H_ * 4);
  half_t* dpad  = (half_t*)alloc((size_t)B_ * 32 * 2);

  // setup (runs every call: harness re-poisons ws)
  k_convert_x<<<(B_ * S_ * IN_) / 256, 256, 0, stream>>>(x, xf, B_ * S_ * IN_);
  k_pack<<<(NG_ * 576) / 256, 256, 0, stream>>>(Wih0e, Whh0e, b0e, Wp0e, bp0e, 64, 64, 576);
  k_pack<<<(NG_ * 1024) / 256, 256, 0, stream>>>(Wih1e, Whh1e, b1e, Wp1e, bp1e, 512, 512, 1024);
  k_pack<<<(NG_ * 544) / 256, 256, 0, stream>>>(Wih0d, Whh0d, b0d, Wp0d, bp0d, 8, 32, 544);
  k_pack<<<(NG_ * 1024) / 256, 256, 0, stream>>>(Wih1d, Whh1d, b1d, Wp1d, bp1d, 512, 512, 1024);
  k_zero_state<<<(B_ * H_) / 256, 256, 0, stream>>>(c0, c1, h0buf[0], h0buf[1],
                                                    h1buf[0], h1buf[1], dpad);

  const dim3 cg(NG_ / 128, B_ / 64);  // 16 x 16

  // encoder
  for (int t = 0; t < S_; ++t) {
    half_t* h0c = h0buf[t & 1];
    half_t* h0p = h0buf[(t + 1) & 1];
    half_t* h1c = h1buf[t & 1];
    half_t* h1p = h1buf[(t + 1) & 1];
    k_cell<<<cg, 256, 0, stream>>>(xf + (size_t)t * IN_, S_ * IN_, 64,
                                   h0p, H_, Wp0e, bp0e, 576, c0, h0c);
    k_cell<<<cg, 256, 0, stream>>>(h0c, H_, 512,
                                   h1p, H_, Wp1e, bp1e, 1024, c1, h1c);
  }
  // decoder
  for (int t = 0; t < HOR_; ++t) {
    const int u = S_ + t;
    half_t* h0c = h0buf[u & 1];
    half_t* h0p = h0buf[(u + 1) & 1];
    half_t* h1c = h1buf[u & 1];
    half_t* h1p = h1buf[(u + 1) & 1];
    k_cell<<<cg, 256, 0, stream>>>(dpad, 32, 32,
                                   h0p, H_, Wp0d, bp0d, 544, c0, h0c);
    k_cell<<<cg, 256, 0, stream>>>(h0c, H_, 512,
                                   h1p, H_, Wp1d, bp1d, 1024, c1, h1c);
    k_fc<<<(B_ * NT_) / 256, 256, 0, stream>>>(h1c, Wfc, bfc, out, dpad, t);
  }
}